// Round 3
// baseline (1395.565 us; speedup 1.0000x reference)
//
#include <hip/hip_runtime.h>
#include <hip/hip_bf16.h>
#include <math.h>

#define NA 50000
#define NS 5000
#define E_AA 500000
#define E_AS 250000
#define CDIM 128
#define ED 8

// ---------------- small helpers ----------------

__device__ inline float4 f4fma(float s, float4 a, float4 b) {   // s*a + b
    return make_float4(fmaf(s, a.x, b.x), fmaf(s, a.y, b.y),
                       fmaf(s, a.z, b.z), fmaf(s, a.w, b.w));
}
__device__ inline float4 f4add(float4 a, float4 b) {
    return make_float4(a.x + b.x, a.y + b.y, a.z + b.z, a.w + b.w);
}
__device__ inline float4 f4leaky(float4 a) {
    return make_float4(a.x > 0.f ? a.x : 0.2f * a.x, a.y > 0.f ? a.y : 0.2f * a.y,
                       a.z > 0.f ? a.z : 0.2f * a.z, a.w > 0.f ? a.w : 0.2f * a.w);
}
__device__ inline float f4dot(float4 a, float4 b) {
    return a.x * b.x + a.y * b.y + a.z * b.z + a.w * b.w;
}
__device__ inline float4 f4mix(float sc, float4 a, float p, float4 x) {  // a*sc + p*x
    return make_float4(fmaf(sc, a.x, p * x.x), fmaf(sc, a.y, p * x.y),
                       fmaf(sc, a.z, p * x.z), fmaf(sc, a.w, p * x.w));
}

// ---------------- CSR build ----------------

__global__ void count_k(const int* __restrict__ dst, int E, int* __restrict__ deg) {
    int e = blockIdx.x * blockDim.x + threadIdx.x;
    if (e < E) atomicAdd(&deg[dst[e]], 1);
}

__global__ __launch_bounds__(1024) void scan_k(const int* __restrict__ deg,
                                               int* __restrict__ row_start, int n) {
    int t = threadIdx.x;
    int per = (n + 1023) / 1024;
    int s0 = t * per;
    int s1 = s0 + per; if (s1 > n) s1 = n;
    int sum = 0;
    for (int i = s0; i < s1; ++i) sum += deg[i];
    __shared__ int wsum[16];
    int lane = t & 63, w = t >> 6;
    int v = sum;
    #pragma unroll
    for (int off = 1; off < 64; off <<= 1) {
        int u = __shfl_up(v, off, 64);
        if (lane >= off) v += u;
    }
    if (lane == 63) wsum[w] = v;
    __syncthreads();
    if (w == 0 && lane < 16) {
        int wv = wsum[lane];
        #pragma unroll
        for (int off = 1; off < 16; off <<= 1) {
            int u = __shfl_up(wv, off, 64);
            if (lane >= off) wv += u;
        }
        wsum[lane] = wv;
    }
    __syncthreads();
    int waveoff = (w > 0) ? wsum[w - 1] : 0;
    int excl = waveoff + v - sum;
    int run = excl;
    for (int i = s0; i < s1; ++i) { row_start[i] = run; run += deg[i]; }
    if (t == 1023) row_start[n] = run;
}

__global__ void scatter_k(const int* __restrict__ dst, int E,
                          const int* __restrict__ row_start,
                          int* __restrict__ cursor, int* __restrict__ csr) {
    int e = blockIdx.x * blockDim.x + threadIdx.x;
    if (e < E) {
        int d = dst[e];
        int pos = atomicAdd(&cursor[d], 1);
        csr[row_start[d] + pos] = e;
    }
}

// ---- degree counting-sort: perm = dst ids ordered by degree ----

__global__ void deghist_k(const int* __restrict__ rs, int n, int* __restrict__ hist) {
    int d = blockIdx.x * blockDim.x + threadIdx.x;
    if (d < n) {
        int deg = rs[d + 1] - rs[d];
        atomicAdd(&hist[deg > 255 ? 255 : deg], 1);
    }
}

__global__ void degscatter_k(const int* __restrict__ rs, int n,
                             const int* __restrict__ binoff, int* __restrict__ cursor,
                             int* __restrict__ perm) {
    int d = blockIdx.x * blockDim.x + threadIdx.x;
    if (d < n) {
        int deg = rs[d + 1] - rs[d];
        if (deg > 255) deg = 255;
        int pos = atomicAdd(&cursor[deg], 1);
        perm[binoff[deg] + pos] = d;
    }
}

// ---------------- single GEMM (style path): Y[N,128] = X[N,K] @ W[K,128] ----------------

template<int K>
__global__ __launch_bounds__(256) void gemm_k(const float* __restrict__ X,
                                              const float* __restrict__ W,
                                              float* __restrict__ Y, int N) {
    __shared__ float Ws[64 * 128];
    __shared__ float Xs[32 * (K + 4)];
    const int XS = K + 4;
    int t = threadIdx.x;
    int rbase = blockIdx.x * 32;

    const int K4 = K / 4;
    const float4* X4 = (const float4*)X;
    for (int i = t; i < 32 * K4; i += 256) {
        int r = i / K4, c4 = i % K4;
        int row = rbase + r;
        float4 v = make_float4(0.f, 0.f, 0.f, 0.f);
        if (row < N) v = X4[(size_t)row * K4 + c4];
        *(float4*)(Xs + r * XS + c4 * 4) = v;
    }

    int cg = t & 31;
    int rq = t >> 5;
    float4 acc[4] = {};
    float4* Ws4 = (float4*)Ws;
    const float4* W4 = (const float4*)W;

    for (int kb = 0; kb < K; kb += 64) {
        __syncthreads();
        for (int i = t; i < 2048; i += 256) Ws4[i] = W4[(size_t)kb * 32 + i];
        __syncthreads();
        #pragma unroll 8
        for (int k2 = 0; k2 < 64; ++k2) {
            float4 w = Ws4[k2 * 32 + cg];
            int k = kb + k2;
            #pragma unroll
            for (int i = 0; i < 4; ++i) {
                float x = Xs[(rq + 8 * i) * XS + k];
                acc[i].x += x * w.x; acc[i].y += x * w.y;
                acc[i].z += x * w.z; acc[i].w += x * w.w;
            }
        }
    }
    #pragma unroll
    for (int i = 0; i < 4; ++i) {
        int row = rbase + rq + 8 * i;
        if (row < N) ((float4*)Y)[(size_t)row * 32 + cg] = acc[i];
    }
}

// ---------------- fused triple GEMM, 64x128 tile, bank-conflict-free ----------------

__global__ __launch_bounds__(256) void gemm3_k(const float* __restrict__ X,
                                               const float* __restrict__ W0,
                                               const float* __restrict__ W1,
                                               const float* __restrict__ W2,
                                               float* __restrict__ Y0,
                                               float* __restrict__ Y1,
                                               float* __restrict__ Y2, int N) {
    __shared__ float Xs[64 * 132];     // stride 132: bank = (4*row + k) % 32
    __shared__ float Ws[32 * 128];
    int t = threadIdx.x;
    int rbase = blockIdx.x * 64;

    const float4* X4 = (const float4*)X;
    for (int i = t; i < 64 * 32; i += 256) {
        int r = i >> 5, c4 = i & 31;
        float4 v = make_float4(0.f, 0.f, 0.f, 0.f);
        if (rbase + r < N) v = X4[(size_t)(rbase + r) * 32 + c4];
        *(float4*)(Xs + r * 132 + c4 * 4) = v;
    }

    int rg = t >> 4;   // 0..15, rows rg + 16*i
    int cg = t & 15;   // cols cg*4..+3 and 64+cg*4..+3
    float4* Ws4 = (float4*)Ws;

    const float* Wp[3] = {W0, W1, W2};
    float* Yp[3] = {Y0, Y1, Y2};

    for (int w = 0; w < 3; ++w) {
        const float4* W4 = (const float4*)Wp[w];
        float4 accA[4] = {}, accB[4] = {};
        for (int kb = 0; kb < 128; kb += 32) {
            __syncthreads();
            for (int i = t; i < 32 * 32; i += 256) Ws4[i] = W4[(size_t)kb * 32 + i];
            __syncthreads();
            #pragma unroll
            for (int k2 = 0; k2 < 32; ++k2) {
                float4 wA = Ws4[k2 * 32 + cg];
                float4 wB = Ws4[k2 * 32 + 16 + cg];
                #pragma unroll
                for (int i = 0; i < 4; ++i) {
                    float x = Xs[(rg + 16 * i) * 132 + kb + k2];
                    accA[i] = f4fma(x, wA, accA[i]);
                    accB[i] = f4fma(x, wB, accB[i]);
                }
            }
        }
        #pragma unroll
        for (int i = 0; i < 4; ++i) {
            int row = rbase + rg + 16 * i;
            if (row < N) {
                float4* yr = (float4*)(Yp[w] + (size_t)row * 128);
                yr[cg] = accA[i];
                yr[16 + cg] = accB[i];
            }
        }
    }
}

// ---------------- fused GATv2 aggregation: 4 dst/wave, 16 lanes/dst ----------------

template<bool RELU>
__global__ __launch_bounds__(256, 2) void agg_k(
    const float* __restrict__ xl, const float* __restrict__ xr,
    const float* __restrict__ eattr, const int* __restrict__ srcv,
    const float* __restrict__ We, const float* __restrict__ att,
    const float* __restrict__ bias, const int* __restrict__ row_start,
    const int* __restrict__ csr_eid, const int* __restrict__ perm,
    float* __restrict__ out, int ndst, int Etot) {
    int wave = threadIdx.x >> 6;
    int lane = threadIdx.x & 63;
    int g = lane >> 4;          // dst group 0..3
    int sl = lane & 15;         // sublane within group
    int c = sl * 8;             // channel base (8 channels/lane)

    int di = blockIdx.x * 16 + wave * 4 + g;
    bool has = di < ndst;
    int d = has ? perm[di] : 0;

    float4 WeA[8], WeB[8];
    #pragma unroll
    for (int k = 0; k < 8; ++k) {
        WeA[k] = *(const float4*)(We + k * 128 + c);
        WeB[k] = *(const float4*)(We + k * 128 + c + 4);
    }
    float4 attA = *(const float4*)(att + c);
    float4 attB = *(const float4*)(att + c + 4);
    float4 bA = *(const float4*)(bias + c);
    float4 bB = *(const float4*)(bias + c + 4);
    float4 xrA = *(const float4*)(xr + (size_t)d * 128 + c);
    float4 xrB = *(const float4*)(xr + (size_t)d * 128 + c + 4);

    float4 accA = {0,0,0,0}, accB = {0,0,0,0};
    float den = 0.f, mrun = -INFINITY;

    int e0 = has ? row_start[d] : 0;
    int cnt = has ? row_start[d + 1] - e0 : 0;

    for (int i = 0; ; i += 4) {
        if (!__any(i < cnt)) break;

        int idx0 = e0 + i, idx1 = idx0 + 1, idx2 = idx0 + 2, idx3 = idx0 + 3;
        int c0 = idx0 < Etot ? idx0 : Etot - 1;
        int c1 = idx1 < Etot ? idx1 : Etot - 1;
        int c2 = idx2 < Etot ? idx2 : Etot - 1;
        int c3 = idx3 < Etot ? idx3 : Etot - 1;
        int ei0 = csr_eid[c0], ei1 = csr_eid[c1], ei2 = csr_eid[c2], ei3 = csr_eid[c3];
        int s0 = srcv[ei0], s1 = srcv[ei1], s2 = srcv[ei2], s3 = srcv[ei3];

        const float4* p0 = (const float4*)(xl + (size_t)s0 * 128 + c);
        const float4* p1 = (const float4*)(xl + (size_t)s1 * 128 + c);
        const float4* p2 = (const float4*)(xl + (size_t)s2 * 128 + c);
        const float4* p3 = (const float4*)(xl + (size_t)s3 * 128 + c);
        float4 x0A = p0[0], x0B = p0[1];
        float4 x1A = p1[0], x1B = p1[1];
        float4 x2A = p2[0], x2B = p2[1];
        float4 x3A = p3[0], x3B = p3[1];
        const float4* q0 = (const float4*)(eattr + (size_t)ei0 * 8);
        const float4* q1 = (const float4*)(eattr + (size_t)ei1 * 8);
        const float4* q2 = (const float4*)(eattr + (size_t)ei2 * 8);
        const float4* q3 = (const float4*)(eattr + (size_t)ei3 * 8);
        float4 e0a = q0[0], e0b = q0[1];
        float4 e1a = q1[0], e1b = q1[1];
        float4 e2a = q2[0], e2b = q2[1];
        float4 e3a = q3[0], e3b = q3[1];

        auto logit = [&](float4 xA, float4 xB, float4 ea, float4 eb) -> float {
            float4 mA = f4add(xA, xrA), mB = f4add(xB, xrB);
            mA = f4fma(ea.x, WeA[0], mA); mB = f4fma(ea.x, WeB[0], mB);
            mA = f4fma(ea.y, WeA[1], mA); mB = f4fma(ea.y, WeB[1], mB);
            mA = f4fma(ea.z, WeA[2], mA); mB = f4fma(ea.z, WeB[2], mB);
            mA = f4fma(ea.w, WeA[3], mA); mB = f4fma(ea.w, WeB[3], mB);
            mA = f4fma(eb.x, WeA[4], mA); mB = f4fma(eb.x, WeB[4], mB);
            mA = f4fma(eb.y, WeA[5], mA); mB = f4fma(eb.y, WeB[5], mB);
            mA = f4fma(eb.z, WeA[6], mA); mB = f4fma(eb.z, WeB[6], mB);
            mA = f4fma(eb.w, WeA[7], mA); mB = f4fma(eb.w, WeB[7], mB);
            return f4dot(f4leaky(mA), attA) + f4dot(f4leaky(mB), attB);
        };

        float t0 = logit(x0A, x0B, e0a, e0b);
        float t1 = logit(x1A, x1B, e1a, e1b);
        float t2 = logit(x2A, x2B, e2a, e2b);
        float t3 = logit(x3A, x3B, e3a, e3b);
        #pragma unroll
        for (int off = 8; off; off >>= 1) {     // reduce within 16-lane group
            t0 += __shfl_xor(t0, off, 64);
            t1 += __shfl_xor(t1, off, 64);
            t2 += __shfl_xor(t2, off, 64);
            t3 += __shfl_xor(t3, off, 64);
        }

        if (i + 0 < cnt) {
            float nm = fmaxf(mrun, t0); float sc = __expf(mrun - nm); float p = __expf(t0 - nm);
            den = den * sc + p; accA = f4mix(sc, accA, p, x0A); accB = f4mix(sc, accB, p, x0B); mrun = nm;
        }
        if (i + 1 < cnt) {
            float nm = fmaxf(mrun, t1); float sc = __expf(mrun - nm); float p = __expf(t1 - nm);
            den = den * sc + p; accA = f4mix(sc, accA, p, x1A); accB = f4mix(sc, accB, p, x1B); mrun = nm;
        }
        if (i + 2 < cnt) {
            float nm = fmaxf(mrun, t2); float sc = __expf(mrun - nm); float p = __expf(t2 - nm);
            den = den * sc + p; accA = f4mix(sc, accA, p, x2A); accB = f4mix(sc, accB, p, x2B); mrun = nm;
        }
        if (i + 3 < cnt) {
            float nm = fmaxf(mrun, t3); float sc = __expf(mrun - nm); float p = __expf(t3 - nm);
            den = den * sc + p; accA = f4mix(sc, accA, p, x3A); accB = f4mix(sc, accB, p, x3B); mrun = nm;
        }
    }

    float inv = 1.f / fmaxf(den, 1e-16f);
    float4 oA = make_float4(accA.x * inv + bA.x, accA.y * inv + bA.y,
                            accA.z * inv + bA.z, accA.w * inv + bA.w);
    float4 oB = make_float4(accB.x * inv + bB.x, accB.y * inv + bB.y,
                            accB.z * inv + bB.z, accB.w * inv + bB.w);
    if (RELU) {
        oA = make_float4(fmaxf(oA.x,0.f), fmaxf(oA.y,0.f), fmaxf(oA.z,0.f), fmaxf(oA.w,0.f));
        oB = make_float4(fmaxf(oB.x,0.f), fmaxf(oB.y,0.f), fmaxf(oB.z,0.f), fmaxf(oB.w,0.f));
    }
    float ss = f4dot(oA, oA) + f4dot(oB, oB);
    #pragma unroll
    for (int off = 8; off; off >>= 1) ss += __shfl_xor(ss, off, 64);
    float innv = 1.f / fmaxf(sqrtf(ss), 1e-12f);
    if (has) {
        float4* op = (float4*)(out + (size_t)d * 128 + c);
        op[0] = make_float4(oA.x * innv, oA.y * innv, oA.z * innv, oA.w * innv);
        op[1] = make_float4(oB.x * innv, oB.y * innv, oB.z * innv, oB.w * innv);
    }
}

// ---------------- launch ----------------

extern "C" void kernel_launch(void* const* d_in, const int* in_sizes, int n_in,
                              void* d_out, int out_size, void* d_ws, size_t ws_size,
                              hipStream_t stream) {
    const float* x_artist = (const float*)d_in[0];
    const float* x_style  = (const float*)d_in[1];
    const int*   src_aa   = (const int*)d_in[2];
    const int*   dst_aa   = (const int*)d_in[3];
    const float* eattr_aa = (const float*)d_in[4];
    const int*   src_as   = (const int*)d_in[5];
    const int*   dst_as   = (const int*)d_in[6];
    const float* eattr_as = (const float*)d_in[7];
    const float* Wl0_aa = (const float*)d_in[8];
    const float* Wr0_aa = (const float*)d_in[9];
    const float* att0_aa = (const float*)d_in[10];
    const float* We0_aa = (const float*)d_in[11];
    const float* b0_aa = (const float*)d_in[12];
    const float* Wl0_as = (const float*)d_in[13];
    const float* Wr0_as = (const float*)d_in[14];
    const float* att0_as = (const float*)d_in[15];
    const float* We0_as = (const float*)d_in[16];
    const float* b0_as = (const float*)d_in[17];
    const float* Wl_aa = (const float*)d_in[18];
    const float* Wr_aa = (const float*)d_in[19];
    const float* att_aa = (const float*)d_in[20];
    const float* We_aa = (const float*)d_in[21];
    const float* b_aa = (const float*)d_in[22];
    const float* Wl_as = (const float*)d_in[23];
    const float* Wr_as = (const float*)d_in[24];
    const float* att_as = (const float*)d_in[25];
    const float* We_as = (const float*)d_in[26];
    const float* b_as = (const float*)d_in[27];

    float* out = (float*)d_out;

    size_t off = 0;
    auto allocf = [&](size_t n) { float* r = (float*)d_ws + off; off += n; return r; };
    float* hA0 = allocf((size_t)NA * CDIM);
    float* hA1 = allocf((size_t)NA * CDIM);
    float* hS0 = allocf((size_t)NS * CDIM);
    float* hS1 = allocf((size_t)NS * CDIM);
    float* bufA = allocf((size_t)NA * CDIM);   // xl_aa
    float* bufB = allocf((size_t)NA * CDIM);   // xr_aa
    float* bufD = allocf((size_t)NA * CDIM);   // xl_as
    float* bufC = allocf((size_t)NS * CDIM);   // xr_as
    int* ip = (int*)((float*)d_ws + off);
    int* rs_aa  = ip;            ip += NA + 1;
    int* cur_aa = ip;            ip += NA;
    int* csr_aa = ip;            ip += E_AA;
    int* rs_as  = ip;            ip += NS + 1;
    int* cur_as = ip;            ip += NS;
    int* csr_as = ip;            ip += E_AS;
    int* perm_aa = ip;           ip += NA;
    int* perm_as = ip;           ip += NS;
    int* dh   = ip;              ip += 256;   // degree histogram
    int* dbo  = ip;              ip += 257;   // bin offsets
    int* dcur = ip;              ip += 256;   // bin cursors

    // ---- CSR + degree-sorted perm, AA ----
    hipMemsetAsync(cur_aa, 0, NA * sizeof(int), stream);
    count_k<<<(E_AA + 255) / 256, 256, 0, stream>>>(dst_aa, E_AA, cur_aa);
    scan_k<<<1, 1024, 0, stream>>>(cur_aa, rs_aa, NA);
    hipMemsetAsync(cur_aa, 0, NA * sizeof(int), stream);
    scatter_k<<<(E_AA + 255) / 256, 256, 0, stream>>>(dst_aa, E_AA, rs_aa, cur_aa, csr_aa);
    hipMemsetAsync(dh, 0, 256 * sizeof(int), stream);
    hipMemsetAsync(dcur, 0, 256 * sizeof(int), stream);
    deghist_k<<<(NA + 255) / 256, 256, 0, stream>>>(rs_aa, NA, dh);
    scan_k<<<1, 1024, 0, stream>>>(dh, dbo, 256);
    degscatter_k<<<(NA + 255) / 256, 256, 0, stream>>>(rs_aa, NA, dbo, dcur, perm_aa);

    // ---- CSR + degree-sorted perm, AS ----
    hipMemsetAsync(cur_as, 0, NS * sizeof(int), stream);
    count_k<<<(E_AS + 255) / 256, 256, 0, stream>>>(dst_as, E_AS, cur_as);
    scan_k<<<1, 1024, 0, stream>>>(cur_as, rs_as, NS);
    hipMemsetAsync(cur_as, 0, NS * sizeof(int), stream);
    scatter_k<<<(E_AS + 255) / 256, 256, 0, stream>>>(dst_as, E_AS, rs_as, cur_as, csr_as);
    hipMemsetAsync(dh, 0, 256 * sizeof(int), stream);
    hipMemsetAsync(dcur, 0, 256 * sizeof(int), stream);
    deghist_k<<<(NS + 255) / 256, 256, 0, stream>>>(rs_as, NS, dh);
    scan_k<<<1, 1024, 0, stream>>>(dh, dbo, 256);
    degscatter_k<<<(NS + 255) / 256, 256, 0, stream>>>(rs_as, NS, dbo, dcur, perm_as);

    const int g3 = (NA + 63) / 64;
    const int gS = (NS + 31) / 32;
    const int aggA = (NA + 15) / 16;
    const int aggS = (NS + 15) / 16;

    const float* hA_in = x_artist;
    const float* hS_in = x_style;

    for (int layer = 0; layer < 3; ++layer) {
        int j = layer - 1;
        const float *pWl_aa, *pWr_aa, *patt_aa, *pWe_aa, *pb_aa;
        const float *pWl_as, *pWr_as, *patt_as, *pWe_as, *pb_as;
        if (layer == 0) {
            pWl_aa = Wl0_aa; pWr_aa = Wr0_aa; patt_aa = att0_aa; pWe_aa = We0_aa; pb_aa = b0_aa;
            pWl_as = Wl0_as; pWr_as = Wr0_as; patt_as = att0_as; pWe_as = We0_as; pb_as = b0_as;
        } else {
            pWl_aa = Wl_aa + (size_t)j * CDIM * CDIM;
            pWr_aa = Wr_aa + (size_t)j * CDIM * CDIM;
            patt_aa = att_aa + (size_t)j * CDIM;
            pWe_aa = We_aa + (size_t)j * ED * CDIM;
            pb_aa = b_aa + (size_t)j * CDIM;
            pWl_as = Wl_as + (size_t)j * CDIM * CDIM;
            pWr_as = Wr_as + (size_t)j * CDIM * CDIM;
            patt_as = att_as + (size_t)j * CDIM;
            pWe_as = We_as + (size_t)j * ED * CDIM;
            pb_as = b_as + (size_t)j * CDIM;
        }
        float* hA_out = (layer == 2) ? out : (layer == 0 ? hA0 : hA1);
        float* hS_out = (layer == 2) ? out + (size_t)NA * CDIM : (layer == 0 ? hS0 : hS1);

        gemm3_k<<<g3, 256, 0, stream>>>(hA_in, pWl_aa, pWr_aa, pWl_as,
                                        bufA, bufB, bufD, NA);
        if (layer == 0)
            gemm_k<64><<<gS, 256, 0, stream>>>(hS_in, pWr_as, bufC, NS);
        else
            gemm_k<128><<<gS, 256, 0, stream>>>(hS_in, pWr_as, bufC, NS);

        if (layer < 2) {
            agg_k<true><<<aggA, 256, 0, stream>>>(bufA, bufB, eattr_aa, src_aa, pWe_aa,
                                                  patt_aa, pb_aa, rs_aa, csr_aa, perm_aa,
                                                  hA_out, NA, E_AA);
            agg_k<true><<<aggS, 256, 0, stream>>>(bufD, bufC, eattr_as, src_as, pWe_as,
                                                  patt_as, pb_as, rs_as, csr_as, perm_as,
                                                  hS_out, NS, E_AS);
        } else {
            agg_k<false><<<aggA, 256, 0, stream>>>(bufA, bufB, eattr_aa, src_aa, pWe_aa,
                                                   patt_aa, pb_aa, rs_aa, csr_aa, perm_aa,
                                                   hA_out, NA, E_AA);
            agg_k<false><<<aggS, 256, 0, stream>>>(bufD, bufC, eattr_as, src_as, pWe_as,
                                                   patt_as, pb_as, rs_as, csr_as, perm_as,
                                                   hS_out, NS, E_AS);
        }

        hA_in = hA_out;
        hS_in = hS_out;
    }
}

// Round 4
// 1042.335 us; speedup vs baseline: 1.3389x; 1.3389x over previous
//
#include <hip/hip_runtime.h>
#include <hip/hip_bf16.h>
#include <math.h>

#define NA 50000
#define NS 5000
#define E_AA 500000
#define E_AS 250000
#define CDIM 128
#define ED 8

// ---------------- small helpers ----------------

__device__ inline float4 f4fma(float s, float4 a, float4 b) {   // s*a + b
    return make_float4(fmaf(s, a.x, b.x), fmaf(s, a.y, b.y),
                       fmaf(s, a.z, b.z), fmaf(s, a.w, b.w));
}
__device__ inline float4 f4add(float4 a, float4 b) {
    return make_float4(a.x + b.x, a.y + b.y, a.z + b.z, a.w + b.w);
}
__device__ inline float4 f4leaky(float4 a) {
    return make_float4(a.x > 0.f ? a.x : 0.2f * a.x, a.y > 0.f ? a.y : 0.2f * a.y,
                       a.z > 0.f ? a.z : 0.2f * a.z, a.w > 0.f ? a.w : 0.2f * a.w);
}
__device__ inline float f4dot(float4 a, float4 b) {
    return a.x * b.x + a.y * b.y + a.z * b.z + a.w * b.w;
}
__device__ inline float4 f4mix(float sc, float4 a, float p, float4 x) {  // a*sc + p*x
    return make_float4(fmaf(sc, a.x, p * x.x), fmaf(sc, a.y, p * x.y),
                       fmaf(sc, a.z, p * x.z), fmaf(sc, a.w, p * x.w));
}

// ---------------- CSR build ----------------

__global__ void count_k(const int* __restrict__ dst, int E, int* __restrict__ deg) {
    int e = blockIdx.x * blockDim.x + threadIdx.x;
    if (e < E) atomicAdd(&deg[dst[e]], 1);
}

__global__ __launch_bounds__(1024) void scan_k(const int* __restrict__ deg,
                                               int* __restrict__ row_start, int n) {
    int t = threadIdx.x;
    int per = (n + 1023) / 1024;
    int s0 = t * per;
    int s1 = s0 + per; if (s1 > n) s1 = n;
    int sum = 0;
    for (int i = s0; i < s1; ++i) sum += deg[i];
    __shared__ int wsum[16];
    int lane = t & 63, w = t >> 6;
    int v = sum;
    #pragma unroll
    for (int off = 1; off < 64; off <<= 1) {
        int u = __shfl_up(v, off, 64);
        if (lane >= off) v += u;
    }
    if (lane == 63) wsum[w] = v;
    __syncthreads();
    if (w == 0 && lane < 16) {
        int wv = wsum[lane];
        #pragma unroll
        for (int off = 1; off < 16; off <<= 1) {
            int u = __shfl_up(wv, off, 64);
            if (lane >= off) wv += u;
        }
        wsum[lane] = wv;
    }
    __syncthreads();
    int waveoff = (w > 0) ? wsum[w - 1] : 0;
    int excl = waveoff + v - sum;
    int run = excl;
    for (int i = s0; i < s1; ++i) { row_start[i] = run; run += deg[i]; }
    if (t == 1023) row_start[n] = run;
}

__global__ void scatter_k(const int* __restrict__ dst, int E,
                          const int* __restrict__ row_start,
                          int* __restrict__ cursor, int* __restrict__ csr) {
    int e = blockIdx.x * blockDim.x + threadIdx.x;
    if (e < E) {
        int d = dst[e];
        int pos = atomicAdd(&cursor[d], 1);
        csr[row_start[d] + pos] = e;
    }
}

// ---- degree counting-sort, two-level (LDS hist first) to kill atomic contention ----

__global__ __launch_bounds__(256) void deghist_k(const int* __restrict__ rs, int n,
                                                 int* __restrict__ hist) {
    __shared__ int lh[256];
    int t = threadIdx.x;
    lh[t] = 0;
    __syncthreads();
    int d = blockIdx.x * 256 + t;
    if (d < n) {
        int deg = rs[d + 1] - rs[d];
        if (deg > 255) deg = 255;
        atomicAdd(&lh[deg], 1);
    }
    __syncthreads();
    if (lh[t]) atomicAdd(&hist[t], lh[t]);
}

__global__ __launch_bounds__(256) void degscatter_k(const int* __restrict__ rs, int n,
                                                    const int* __restrict__ binoff,
                                                    int* __restrict__ cursor,
                                                    int* __restrict__ perm) {
    __shared__ int lh[256];
    __shared__ int lbase[256];
    int t = threadIdx.x;
    lh[t] = 0;
    __syncthreads();
    int d = blockIdx.x * 256 + t;
    int deg = 0, lpos = 0;
    if (d < n) {
        deg = rs[d + 1] - rs[d];
        if (deg > 255) deg = 255;
        lpos = atomicAdd(&lh[deg], 1);      // local rank within (block, bin)
    }
    __syncthreads();
    int cnt = lh[t];
    if (cnt) lbase[t] = atomicAdd(&cursor[t], cnt);   // reserve block's slice of bin t
    __syncthreads();
    if (d < n) perm[binoff[deg] + lbase[deg] + lpos] = d;
}

// ---------------- single GEMM (style path): Y[N,128] = X[N,K] @ W[K,128] ----------------

template<int K>
__global__ __launch_bounds__(256) void gemm_k(const float* __restrict__ X,
                                              const float* __restrict__ W,
                                              float* __restrict__ Y, int N) {
    __shared__ float Ws[64 * 128];
    __shared__ float Xs[32 * (K + 4)];
    const int XS = K + 4;
    int t = threadIdx.x;
    int rbase = blockIdx.x * 32;

    const int K4 = K / 4;
    const float4* X4 = (const float4*)X;
    for (int i = t; i < 32 * K4; i += 256) {
        int r = i / K4, c4 = i % K4;
        int row = rbase + r;
        float4 v = make_float4(0.f, 0.f, 0.f, 0.f);
        if (row < N) v = X4[(size_t)row * K4 + c4];
        *(float4*)(Xs + r * XS + c4 * 4) = v;
    }

    int cg = t & 31;
    int rq = t >> 5;
    float4 acc[4] = {};
    float4* Ws4 = (float4*)Ws;
    const float4* W4 = (const float4*)W;

    for (int kb = 0; kb < K; kb += 64) {
        __syncthreads();
        for (int i = t; i < 2048; i += 256) Ws4[i] = W4[(size_t)kb * 32 + i];
        __syncthreads();
        #pragma unroll 8
        for (int k2 = 0; k2 < 64; ++k2) {
            float4 w = Ws4[k2 * 32 + cg];
            int k = kb + k2;
            #pragma unroll
            for (int i = 0; i < 4; ++i) {
                float x = Xs[(rq + 8 * i) * XS + k];
                acc[i].x += x * w.x; acc[i].y += x * w.y;
                acc[i].z += x * w.z; acc[i].w += x * w.w;
            }
        }
    }
    #pragma unroll
    for (int i = 0; i < 4; ++i) {
        int row = rbase + rq + 8 * i;
        if (row < N) ((float4*)Y)[(size_t)row * 32 + cg] = acc[i];
    }
}

// ---------------- fused triple GEMM, 64x128 tile, bank-conflict-free ----------------

__global__ __launch_bounds__(256) void gemm3_k(const float* __restrict__ X,
                                               const float* __restrict__ W0,
                                               const float* __restrict__ W1,
                                               const float* __restrict__ W2,
                                               float* __restrict__ Y0,
                                               float* __restrict__ Y1,
                                               float* __restrict__ Y2, int N) {
    __shared__ float Xs[64 * 132];     // stride 132: bank = (4*row + k) % 32
    __shared__ float Ws[32 * 128];
    int t = threadIdx.x;
    int rbase = blockIdx.x * 64;

    const float4* X4 = (const float4*)X;
    for (int i = t; i < 64 * 32; i += 256) {
        int r = i >> 5, c4 = i & 31;
        float4 v = make_float4(0.f, 0.f, 0.f, 0.f);
        if (rbase + r < N) v = X4[(size_t)(rbase + r) * 32 + c4];
        *(float4*)(Xs + r * 132 + c4 * 4) = v;
    }

    int rg = t >> 4;   // 0..15, rows rg + 16*i
    int cg = t & 15;   // cols cg*4..+3 and 64+cg*4..+3
    float4* Ws4 = (float4*)Ws;

    const float* Wp[3] = {W0, W1, W2};
    float* Yp[3] = {Y0, Y1, Y2};

    for (int w = 0; w < 3; ++w) {
        const float4* W4 = (const float4*)Wp[w];
        float4 accA[4] = {}, accB[4] = {};
        for (int kb = 0; kb < 128; kb += 32) {
            __syncthreads();
            for (int i = t; i < 32 * 32; i += 256) Ws4[i] = W4[(size_t)kb * 32 + i];
            __syncthreads();
            #pragma unroll
            for (int k2 = 0; k2 < 32; ++k2) {
                float4 wA = Ws4[k2 * 32 + cg];
                float4 wB = Ws4[k2 * 32 + 16 + cg];
                #pragma unroll
                for (int i = 0; i < 4; ++i) {
                    float x = Xs[(rg + 16 * i) * 132 + kb + k2];
                    accA[i] = f4fma(x, wA, accA[i]);
                    accB[i] = f4fma(x, wB, accB[i]);
                }
            }
        }
        #pragma unroll
        for (int i = 0; i < 4; ++i) {
            int row = rbase + rg + 16 * i;
            if (row < N) {
                float4* yr = (float4*)(Yp[w] + (size_t)row * 128);
                yr[cg] = accA[i];
                yr[16 + cg] = accB[i];
            }
        }
    }
}

// ---------------- fused GATv2 aggregation: 4 dst/wave, 16 lanes/dst ----------------

template<bool RELU>
__global__ __launch_bounds__(256, 2) void agg_k(
    const float* __restrict__ xl, const float* __restrict__ xr,
    const float* __restrict__ eattr, const int* __restrict__ srcv,
    const float* __restrict__ We, const float* __restrict__ att,
    const float* __restrict__ bias, const int* __restrict__ row_start,
    const int* __restrict__ csr_eid, const int* __restrict__ perm,
    float* __restrict__ out, int ndst, int Etot) {
    int wave = threadIdx.x >> 6;
    int lane = threadIdx.x & 63;
    int g = lane >> 4;          // dst group 0..3
    int sl = lane & 15;         // sublane within group
    int c = sl * 8;             // channel base (8 channels/lane)

    int di = blockIdx.x * 16 + wave * 4 + g;
    bool has = di < ndst;
    int d = has ? perm[di] : 0;

    float4 WeA[8], WeB[8];
    #pragma unroll
    for (int k = 0; k < 8; ++k) {
        WeA[k] = *(const float4*)(We + k * 128 + c);
        WeB[k] = *(const float4*)(We + k * 128 + c + 4);
    }
    float4 attA = *(const float4*)(att + c);
    float4 attB = *(const float4*)(att + c + 4);
    float4 bA = *(const float4*)(bias + c);
    float4 bB = *(const float4*)(bias + c + 4);
    float4 xrA = *(const float4*)(xr + (size_t)d * 128 + c);
    float4 xrB = *(const float4*)(xr + (size_t)d * 128 + c + 4);

    float4 accA = {0,0,0,0}, accB = {0,0,0,0};
    float den = 0.f, mrun = -INFINITY;

    int e0 = has ? row_start[d] : 0;
    int cnt = has ? row_start[d + 1] - e0 : 0;

    for (int i = 0; ; i += 4) {
        if (!__any(i < cnt)) break;

        int idx0 = e0 + i, idx1 = idx0 + 1, idx2 = idx0 + 2, idx3 = idx0 + 3;
        int c0 = idx0 < Etot ? idx0 : Etot - 1;
        int c1 = idx1 < Etot ? idx1 : Etot - 1;
        int c2 = idx2 < Etot ? idx2 : Etot - 1;
        int c3 = idx3 < Etot ? idx3 : Etot - 1;
        int ei0 = csr_eid[c0], ei1 = csr_eid[c1], ei2 = csr_eid[c2], ei3 = csr_eid[c3];
        int s0 = srcv[ei0], s1 = srcv[ei1], s2 = srcv[ei2], s3 = srcv[ei3];

        const float4* p0 = (const float4*)(xl + (size_t)s0 * 128 + c);
        const float4* p1 = (const float4*)(xl + (size_t)s1 * 128 + c);
        const float4* p2 = (const float4*)(xl + (size_t)s2 * 128 + c);
        const float4* p3 = (const float4*)(xl + (size_t)s3 * 128 + c);
        float4 x0A = p0[0], x0B = p0[1];
        float4 x1A = p1[0], x1B = p1[1];
        float4 x2A = p2[0], x2B = p2[1];
        float4 x3A = p3[0], x3B = p3[1];
        const float4* q0 = (const float4*)(eattr + (size_t)ei0 * 8);
        const float4* q1 = (const float4*)(eattr + (size_t)ei1 * 8);
        const float4* q2 = (const float4*)(eattr + (size_t)ei2 * 8);
        const float4* q3 = (const float4*)(eattr + (size_t)ei3 * 8);
        float4 e0a = q0[0], e0b = q0[1];
        float4 e1a = q1[0], e1b = q1[1];
        float4 e2a = q2[0], e2b = q2[1];
        float4 e3a = q3[0], e3b = q3[1];

        auto logit = [&](float4 xA, float4 xB, float4 ea, float4 eb) -> float {
            float4 mA = f4add(xA, xrA), mB = f4add(xB, xrB);
            mA = f4fma(ea.x, WeA[0], mA); mB = f4fma(ea.x, WeB[0], mB);
            mA = f4fma(ea.y, WeA[1], mA); mB = f4fma(ea.y, WeB[1], mB);
            mA = f4fma(ea.z, WeA[2], mA); mB = f4fma(ea.z, WeB[2], mB);
            mA = f4fma(ea.w, WeA[3], mA); mB = f4fma(ea.w, WeB[3], mB);
            mA = f4fma(eb.x, WeA[4], mA); mB = f4fma(eb.x, WeB[4], mB);
            mA = f4fma(eb.y, WeA[5], mA); mB = f4fma(eb.y, WeB[5], mB);
            mA = f4fma(eb.z, WeA[6], mA); mB = f4fma(eb.z, WeB[6], mB);
            mA = f4fma(eb.w, WeA[7], mA); mB = f4fma(eb.w, WeB[7], mB);
            return f4dot(f4leaky(mA), attA) + f4dot(f4leaky(mB), attB);
        };

        float t0 = logit(x0A, x0B, e0a, e0b);
        float t1 = logit(x1A, x1B, e1a, e1b);
        float t2 = logit(x2A, x2B, e2a, e2b);
        float t3 = logit(x3A, x3B, e3a, e3b);
        #pragma unroll
        for (int off = 8; off; off >>= 1) {     // reduce within 16-lane group
            t0 += __shfl_xor(t0, off, 64);
            t1 += __shfl_xor(t1, off, 64);
            t2 += __shfl_xor(t2, off, 64);
            t3 += __shfl_xor(t3, off, 64);
        }

        if (i + 0 < cnt) {
            float nm = fmaxf(mrun, t0); float sc = __expf(mrun - nm); float p = __expf(t0 - nm);
            den = den * sc + p; accA = f4mix(sc, accA, p, x0A); accB = f4mix(sc, accB, p, x0B); mrun = nm;
        }
        if (i + 1 < cnt) {
            float nm = fmaxf(mrun, t1); float sc = __expf(mrun - nm); float p = __expf(t1 - nm);
            den = den * sc + p; accA = f4mix(sc, accA, p, x1A); accB = f4mix(sc, accB, p, x1B); mrun = nm;
        }
        if (i + 2 < cnt) {
            float nm = fmaxf(mrun, t2); float sc = __expf(mrun - nm); float p = __expf(t2 - nm);
            den = den * sc + p; accA = f4mix(sc, accA, p, x2A); accB = f4mix(sc, accB, p, x2B); mrun = nm;
        }
        if (i + 3 < cnt) {
            float nm = fmaxf(mrun, t3); float sc = __expf(mrun - nm); float p = __expf(t3 - nm);
            den = den * sc + p; accA = f4mix(sc, accA, p, x3A); accB = f4mix(sc, accB, p, x3B); mrun = nm;
        }
    }

    float inv = 1.f / fmaxf(den, 1e-16f);
    float4 oA = make_float4(accA.x * inv + bA.x, accA.y * inv + bA.y,
                            accA.z * inv + bA.z, accA.w * inv + bA.w);
    float4 oB = make_float4(accB.x * inv + bB.x, accB.y * inv + bB.y,
                            accB.z * inv + bB.z, accB.w * inv + bB.w);
    if (RELU) {
        oA = make_float4(fmaxf(oA.x,0.f), fmaxf(oA.y,0.f), fmaxf(oA.z,0.f), fmaxf(oA.w,0.f));
        oB = make_float4(fmaxf(oB.x,0.f), fmaxf(oB.y,0.f), fmaxf(oB.z,0.f), fmaxf(oB.w,0.f));
    }
    float ss = f4dot(oA, oA) + f4dot(oB, oB);
    #pragma unroll
    for (int off = 8; off; off >>= 1) ss += __shfl_xor(ss, off, 64);
    float innv = 1.f / fmaxf(sqrtf(ss), 1e-12f);
    if (has) {
        float4* op = (float4*)(out + (size_t)d * 128 + c);
        op[0] = make_float4(oA.x * innv, oA.y * innv, oA.z * innv, oA.w * innv);
        op[1] = make_float4(oB.x * innv, oB.y * innv, oB.z * innv, oB.w * innv);
    }
}

// ---------------- launch ----------------

extern "C" void kernel_launch(void* const* d_in, const int* in_sizes, int n_in,
                              void* d_out, int out_size, void* d_ws, size_t ws_size,
                              hipStream_t stream) {
    const float* x_artist = (const float*)d_in[0];
    const float* x_style  = (const float*)d_in[1];
    const int*   src_aa   = (const int*)d_in[2];
    const int*   dst_aa   = (const int*)d_in[3];
    const float* eattr_aa = (const float*)d_in[4];
    const int*   src_as   = (const int*)d_in[5];
    const int*   dst_as   = (const int*)d_in[6];
    const float* eattr_as = (const float*)d_in[7];
    const float* Wl0_aa = (const float*)d_in[8];
    const float* Wr0_aa = (const float*)d_in[9];
    const float* att0_aa = (const float*)d_in[10];
    const float* We0_aa = (const float*)d_in[11];
    const float* b0_aa = (const float*)d_in[12];
    const float* Wl0_as = (const float*)d_in[13];
    const float* Wr0_as = (const float*)d_in[14];
    const float* att0_as = (const float*)d_in[15];
    const float* We0_as = (const float*)d_in[16];
    const float* b0_as = (const float*)d_in[17];
    const float* Wl_aa = (const float*)d_in[18];
    const float* Wr_aa = (const float*)d_in[19];
    const float* att_aa = (const float*)d_in[20];
    const float* We_aa = (const float*)d_in[21];
    const float* b_aa = (const float*)d_in[22];
    const float* Wl_as = (const float*)d_in[23];
    const float* Wr_as = (const float*)d_in[24];
    const float* att_as = (const float*)d_in[25];
    const float* We_as = (const float*)d_in[26];
    const float* b_as = (const float*)d_in[27];

    float* out = (float*)d_out;

    size_t off = 0;
    auto allocf = [&](size_t n) { float* r = (float*)d_ws + off; off += n; return r; };
    float* hA0 = allocf((size_t)NA * CDIM);
    float* hA1 = allocf((size_t)NA * CDIM);
    float* hS0 = allocf((size_t)NS * CDIM);
    float* hS1 = allocf((size_t)NS * CDIM);
    float* bufA = allocf((size_t)NA * CDIM);   // xl_aa
    float* bufB = allocf((size_t)NA * CDIM);   // xr_aa
    float* bufD = allocf((size_t)NA * CDIM);   // xl_as
    float* bufC = allocf((size_t)NS * CDIM);   // xr_as
    int* ip = (int*)((float*)d_ws + off);
    int* rs_aa  = ip;            ip += NA + 1;
    int* cur_aa = ip;            ip += NA;
    int* csr_aa = ip;            ip += E_AA;
    int* rs_as  = ip;            ip += NS + 1;
    int* cur_as = ip;            ip += NS;
    int* csr_as = ip;            ip += E_AS;
    int* perm_aa = ip;           ip += NA;
    int* perm_as = ip;           ip += NS;
    int* dh   = ip;              ip += 256;   // degree histogram
    int* dbo  = ip;              ip += 257;   // bin offsets
    int* dcur = ip;              ip += 256;   // bin cursors

    // ---- CSR + degree-sorted perm, AA ----
    hipMemsetAsync(cur_aa, 0, NA * sizeof(int), stream);
    count_k<<<(E_AA + 255) / 256, 256, 0, stream>>>(dst_aa, E_AA, cur_aa);
    scan_k<<<1, 1024, 0, stream>>>(cur_aa, rs_aa, NA);
    hipMemsetAsync(cur_aa, 0, NA * sizeof(int), stream);
    scatter_k<<<(E_AA + 255) / 256, 256, 0, stream>>>(dst_aa, E_AA, rs_aa, cur_aa, csr_aa);
    hipMemsetAsync(dh, 0, 256 * sizeof(int), stream);
    hipMemsetAsync(dcur, 0, 256 * sizeof(int), stream);
    deghist_k<<<(NA + 255) / 256, 256, 0, stream>>>(rs_aa, NA, dh);
    scan_k<<<1, 1024, 0, stream>>>(dh, dbo, 256);
    degscatter_k<<<(NA + 255) / 256, 256, 0, stream>>>(rs_aa, NA, dbo, dcur, perm_aa);

    // ---- CSR + degree-sorted perm, AS ----
    hipMemsetAsync(cur_as, 0, NS * sizeof(int), stream);
    count_k<<<(E_AS + 255) / 256, 256, 0, stream>>>(dst_as, E_AS, cur_as);
    scan_k<<<1, 1024, 0, stream>>>(cur_as, rs_as, NS);
    hipMemsetAsync(cur_as, 0, NS * sizeof(int), stream);
    scatter_k<<<(E_AS + 255) / 256, 256, 0, stream>>>(dst_as, E_AS, rs_as, cur_as, csr_as);
    hipMemsetAsync(dh, 0, 256 * sizeof(int), stream);
    hipMemsetAsync(dcur, 0, 256 * sizeof(int), stream);
    deghist_k<<<(NS + 255) / 256, 256, 0, stream>>>(rs_as, NS, dh);
    scan_k<<<1, 1024, 0, stream>>>(dh, dbo, 256);
    degscatter_k<<<(NS + 255) / 256, 256, 0, stream>>>(rs_as, NS, dbo, dcur, perm_as);

    const int g3 = (NA + 63) / 64;
    const int gS = (NS + 31) / 32;
    const int aggA = (NA + 15) / 16;
    const int aggS = (NS + 15) / 16;

    const float* hA_in = x_artist;
    const float* hS_in = x_style;

    for (int layer = 0; layer < 3; ++layer) {
        int j = layer - 1;
        const float *pWl_aa, *pWr_aa, *patt_aa, *pWe_aa, *pb_aa;
        const float *pWl_as, *pWr_as, *patt_as, *pWe_as, *pb_as;
        if (layer == 0) {
            pWl_aa = Wl0_aa; pWr_aa = Wr0_aa; patt_aa = att0_aa; pWe_aa = We0_aa; pb_aa = b0_aa;
            pWl_as = Wl0_as; pWr_as = Wr0_as; patt_as = att0_as; pWe_as = We0_as; pb_as = b0_as;
        } else {
            pWl_aa = Wl_aa + (size_t)j * CDIM * CDIM;
            pWr_aa = Wr_aa + (size_t)j * CDIM * CDIM;
            patt_aa = att_aa + (size_t)j * CDIM;
            pWe_aa = We_aa + (size_t)j * ED * CDIM;
            pb_aa = b_aa + (size_t)j * CDIM;
            pWl_as = Wl_as + (size_t)j * CDIM * CDIM;
            pWr_as = Wr_as + (size_t)j * CDIM * CDIM;
            patt_as = att_as + (size_t)j * CDIM;
            pWe_as = We_as + (size_t)j * ED * CDIM;
            pb_as = b_as + (size_t)j * CDIM;
        }
        float* hA_out = (layer == 2) ? out : (layer == 0 ? hA0 : hA1);
        float* hS_out = (layer == 2) ? out + (size_t)NA * CDIM : (layer == 0 ? hS0 : hS1);

        gemm3_k<<<g3, 256, 0, stream>>>(hA_in, pWl_aa, pWr_aa, pWl_as,
                                        bufA, bufB, bufD, NA);
        if (layer == 0)
            gemm_k<64><<<gS, 256, 0, stream>>>(hS_in, pWr_as, bufC, NS);
        else
            gemm_k<128><<<gS, 256, 0, stream>>>(hS_in, pWr_as, bufC, NS);

        if (layer < 2) {
            agg_k<true><<<aggA, 256, 0, stream>>>(bufA, bufB, eattr_aa, src_aa, pWe_aa,
                                                  patt_aa, pb_aa, rs_aa, csr_aa, perm_aa,
                                                  hA_out, NA, E_AA);
            agg_k<true><<<aggS, 256, 0, stream>>>(bufD, bufC, eattr_as, src_as, pWe_as,
                                                  patt_as, pb_as, rs_as, csr_as, perm_as,
                                                  hS_out, NS, E_AS);
        } else {
            agg_k<false><<<aggA, 256, 0, stream>>>(bufA, bufB, eattr_aa, src_aa, pWe_aa,
                                                   patt_aa, pb_aa, rs_aa, csr_aa, perm_aa,
                                                   hA_out, NA, E_AA);
            agg_k<false><<<aggS, 256, 0, stream>>>(bufD, bufC, eattr_as, src_as, pWe_as,
                                                   patt_as, pb_as, rs_as, csr_as, perm_as,
                                                   hS_out, NS, E_AS);
        }

        hA_in = hA_out;
        hS_in = hS_out;
    }
}

// Round 5
// 939.508 us; speedup vs baseline: 1.4854x; 1.1094x over previous
//
#include <hip/hip_runtime.h>
#include <hip/hip_bf16.h>
#include <math.h>

#define NA 50000
#define NS 5000
#define E_AA 500000
#define E_AS 250000
#define CDIM 128
#define ED 8
#define NAPAD 50048   // 782*64

typedef __attribute__((ext_vector_type(8))) short bf16x8;
typedef __attribute__((ext_vector_type(4))) float f32x4;

__device__ inline short f2bf(float f) {
    __hip_bfloat16 h = __float2bfloat16(f);
    return *(short*)&h;
}

// ---------------- small helpers ----------------

__device__ inline float4 f4fma(float s, float4 a, float4 b) {
    return make_float4(fmaf(s, a.x, b.x), fmaf(s, a.y, b.y),
                       fmaf(s, a.z, b.z), fmaf(s, a.w, b.w));
}
__device__ inline float4 f4add(float4 a, float4 b) {
    return make_float4(a.x + b.x, a.y + b.y, a.z + b.z, a.w + b.w);
}
__device__ inline float4 f4leaky(float4 a) {
    return make_float4(a.x > 0.f ? a.x : 0.2f * a.x, a.y > 0.f ? a.y : 0.2f * a.y,
                       a.z > 0.f ? a.z : 0.2f * a.z, a.w > 0.f ? a.w : 0.2f * a.w);
}
__device__ inline float f4dot(float4 a, float4 b) {
    return a.x * b.x + a.y * b.y + a.z * b.z + a.w * b.w;
}
__device__ inline float4 f4mix(float sc, float4 a, float p, float4 x) {
    return make_float4(fmaf(sc, a.x, p * x.x), fmaf(sc, a.y, p * x.y),
                       fmaf(sc, a.z, p * x.z), fmaf(sc, a.w, p * x.w));
}

// ---------------- CSR build ----------------

__global__ void count_k(const int* __restrict__ dst, int E, int* __restrict__ deg) {
    int e = blockIdx.x * blockDim.x + threadIdx.x;
    if (e < E) atomicAdd(&deg[dst[e]], 1);
}

__global__ __launch_bounds__(1024) void scan_k(const int* __restrict__ deg,
                                               int* __restrict__ row_start, int n) {
    int t = threadIdx.x;
    int per = (n + 1023) / 1024;
    int s0 = t * per;
    int s1 = s0 + per; if (s1 > n) s1 = n;
    int sum = 0;
    for (int i = s0; i < s1; ++i) sum += deg[i];
    __shared__ int wsum[16];
    int lane = t & 63, w = t >> 6;
    int v = sum;
    #pragma unroll
    for (int off = 1; off < 64; off <<= 1) {
        int u = __shfl_up(v, off, 64);
        if (lane >= off) v += u;
    }
    if (lane == 63) wsum[w] = v;
    __syncthreads();
    if (w == 0 && lane < 16) {
        int wv = wsum[lane];
        #pragma unroll
        for (int off = 1; off < 16; off <<= 1) {
            int u = __shfl_up(wv, off, 64);
            if (lane >= off) wv += u;
        }
        wsum[lane] = wv;
    }
    __syncthreads();
    int waveoff = (w > 0) ? wsum[w - 1] : 0;
    int excl = waveoff + v - sum;
    int run = excl;
    for (int i = s0; i < s1; ++i) { row_start[i] = run; run += deg[i]; }
    if (t == 1023) row_start[n] = run;
}

__global__ void scatter_k(const int* __restrict__ dst, int E,
                          const int* __restrict__ row_start,
                          int* __restrict__ cursor, int* __restrict__ csr) {
    int e = blockIdx.x * blockDim.x + threadIdx.x;
    if (e < E) {
        int d = dst[e];
        int pos = atomicAdd(&cursor[d], 1);
        csr[row_start[d] + pos] = e;
    }
}

// ---- degree counting-sort, two-level (LDS hist) ----

__global__ __launch_bounds__(256) void deghist_k(const int* __restrict__ rs, int n,
                                                 int* __restrict__ hist) {
    __shared__ int lh[256];
    int t = threadIdx.x;
    lh[t] = 0;
    __syncthreads();
    int d = blockIdx.x * 256 + t;
    if (d < n) {
        int deg = rs[d + 1] - rs[d];
        if (deg > 255) deg = 255;
        atomicAdd(&lh[deg], 1);
    }
    __syncthreads();
    if (lh[t]) atomicAdd(&hist[t], lh[t]);
}

__global__ __launch_bounds__(256) void degscatter_k(const int* __restrict__ rs, int n,
                                                    const int* __restrict__ binoff,
                                                    int* __restrict__ cursor,
                                                    int* __restrict__ perm) {
    __shared__ int lh[256];
    __shared__ int lbase[256];
    int t = threadIdx.x;
    lh[t] = 0;
    __syncthreads();
    int d = blockIdx.x * 256 + t;
    int deg = 0, lpos = 0;
    if (d < n) {
        deg = rs[d + 1] - rs[d];
        if (deg > 255) deg = 255;
        lpos = atomicAdd(&lh[deg], 1);
    }
    __syncthreads();
    int cnt = lh[t];
    if (cnt) lbase[t] = atomicAdd(&cursor[t], cnt);
    __syncthreads();
    if (d < n) perm[binoff[deg] + lbase[deg] + lpos] = d;
}

// ---------------- f32 -> bf16 convert (layer 0 X) ----------------

__global__ __launch_bounds__(256) void cvt_k(const float* __restrict__ in,
                                             short* __restrict__ out, int n4) {
    int i = blockIdx.x * 256 + threadIdx.x;
    if (i < n4) {
        float4 v = ((const float4*)in)[i];
        short4 s;
        s.x = f2bf(v.x); s.y = f2bf(v.y); s.z = f2bf(v.z); s.w = f2bf(v.w);
        ((short4*)out)[i] = s;
    }
}

// ---------------- W transpose+convert: Wt[w][n][k] bf16 ----------------

__global__ __launch_bounds__(256) void wtr_k(const float* __restrict__ W0,
                                             const float* __restrict__ W1,
                                             const float* __restrict__ W2,
                                             short* __restrict__ Wt) {
    int w = blockIdx.x >> 6;
    int idx = (blockIdx.x & 63) * 256 + threadIdx.x;  // 0..16383
    int k = idx >> 7, n = idx & 127;
    const float* W = (w == 0) ? W0 : ((w == 1) ? W1 : W2);
    Wt[w * 16384 + n * 128 + k] = f2bf(W[idx]);
}

// ---------------- MFMA triple GEMM: Yi[N,128] = Xb[N,128] @ Wi ----------------
// Xb bf16 row-major; Wt[w][n][k] bf16 (transposed). No LDS.

__global__ __launch_bounds__(256) void gemm3_mfma_k(
    const short* __restrict__ Xb, const short* __restrict__ Wt,
    float* __restrict__ Y0, float* __restrict__ Y1, float* __restrict__ Y2, int N) {
    int t = threadIdx.x;
    int wave = t >> 6, lane = t & 63;
    int quad = lane >> 4, l16 = lane & 15;
    int rbase = blockIdx.x * 64 + wave * 16;

    bf16x8 a[4];
    const short* arow = Xb + (size_t)(rbase + l16) * 128 + quad * 8;
    #pragma unroll
    for (int kb = 0; kb < 4; ++kb) a[kb] = *(const bf16x8*)(arow + kb * 32);

    float* Yp[3] = {Y0, Y1, Y2};
    for (int w = 0; w < 3; ++w) {
        const short* Wb = Wt + (size_t)w * 16384;
        #pragma unroll
        for (int nt = 0; nt < 8; ++nt) {
            f32x4 acc = {0.f, 0.f, 0.f, 0.f};
            const short* brow = Wb + (size_t)(nt * 16 + l16) * 128 + quad * 8;
            #pragma unroll
            for (int kb = 0; kb < 4; ++kb) {
                bf16x8 b = *(const bf16x8*)(brow + kb * 32);
                acc = __builtin_amdgcn_mfma_f32_16x16x32_bf16(a[kb], b, acc, 0, 0, 0);
            }
            int col = nt * 16 + l16;
            #pragma unroll
            for (int r = 0; r < 4; ++r) {
                int row = rbase + quad * 4 + r;
                if (row < N) Yp[w][(size_t)row * 128 + col] = acc[r];
            }
        }
    }
}

// ---------------- single GEMM (style path): Y[N,128] = X[N,K] @ W[K,128] ----------------

template<int K>
__global__ __launch_bounds__(256) void gemm_k(const float* __restrict__ X,
                                              const float* __restrict__ W,
                                              float* __restrict__ Y, int N) {
    __shared__ float Ws[64 * 128];
    __shared__ float Xs[32 * (K + 4)];
    const int XS = K + 4;
    int t = threadIdx.x;
    int rbase = blockIdx.x * 32;

    const int K4 = K / 4;
    const float4* X4 = (const float4*)X;
    for (int i = t; i < 32 * K4; i += 256) {
        int r = i / K4, c4 = i % K4;
        int row = rbase + r;
        float4 v = make_float4(0.f, 0.f, 0.f, 0.f);
        if (row < N) v = X4[(size_t)row * K4 + c4];
        *(float4*)(Xs + r * XS + c4 * 4) = v;
    }

    int cg = t & 31;
    int rq = t >> 5;
    float4 acc[4] = {};
    float4* Ws4 = (float4*)Ws;
    const float4* W4 = (const float4*)W;

    for (int kb = 0; kb < K; kb += 64) {
        __syncthreads();
        for (int i = t; i < 2048; i += 256) Ws4[i] = W4[(size_t)kb * 32 + i];
        __syncthreads();
        #pragma unroll 8
        for (int k2 = 0; k2 < 64; ++k2) {
            float4 w = Ws4[k2 * 32 + cg];
            int k = kb + k2;
            #pragma unroll
            for (int i = 0; i < 4; ++i) {
                float x = Xs[(rq + 8 * i) * XS + k];
                acc[i].x += x * w.x; acc[i].y += x * w.y;
                acc[i].z += x * w.z; acc[i].w += x * w.w;
            }
        }
    }
    #pragma unroll
    for (int i = 0; i < 4; ++i) {
        int row = rbase + rq + 8 * i;
        if (row < N) ((float4*)Y)[(size_t)row * 32 + cg] = acc[i];
    }
}

// ---------------- fused GATv2 aggregation: 4 dst/wave, 16 lanes/dst ----------------
// optional secondary bf16 output (next layer's MFMA operand)

template<bool RELU>
__global__ __launch_bounds__(256, 2) void agg_k(
    const float* __restrict__ xl, const float* __restrict__ xr,
    const float* __restrict__ eattr, const int* __restrict__ srcv,
    const float* __restrict__ We, const float* __restrict__ att,
    const float* __restrict__ bias, const int* __restrict__ row_start,
    const int* __restrict__ csr_eid, const int* __restrict__ perm,
    float* __restrict__ out, short* __restrict__ outb, int ndst, int Etot) {
    int wave = threadIdx.x >> 6;
    int lane = threadIdx.x & 63;
    int g = lane >> 4;
    int sl = lane & 15;
    int c = sl * 8;

    int di = blockIdx.x * 16 + wave * 4 + g;
    bool has = di < ndst;
    int d = has ? perm[di] : 0;

    float4 WeA[8], WeB[8];
    #pragma unroll
    for (int k = 0; k < 8; ++k) {
        WeA[k] = *(const float4*)(We + k * 128 + c);
        WeB[k] = *(const float4*)(We + k * 128 + c + 4);
    }
    float4 attA = *(const float4*)(att + c);
    float4 attB = *(const float4*)(att + c + 4);
    float4 bA = *(const float4*)(bias + c);
    float4 bB = *(const float4*)(bias + c + 4);
    float4 xrA = *(const float4*)(xr + (size_t)d * 128 + c);
    float4 xrB = *(const float4*)(xr + (size_t)d * 128 + c + 4);

    float4 accA = {0,0,0,0}, accB = {0,0,0,0};
    float den = 0.f, mrun = -INFINITY;

    int e0 = has ? row_start[d] : 0;
    int cnt = has ? row_start[d + 1] - e0 : 0;

    for (int i = 0; ; i += 4) {
        if (!__any(i < cnt)) break;

        int idx0 = e0 + i;
        int c0 = idx0 < Etot ? idx0 : Etot - 1;
        int c1 = idx0 + 1 < Etot ? idx0 + 1 : Etot - 1;
        int c2 = idx0 + 2 < Etot ? idx0 + 2 : Etot - 1;
        int c3 = idx0 + 3 < Etot ? idx0 + 3 : Etot - 1;
        int ei0 = csr_eid[c0], ei1 = csr_eid[c1], ei2 = csr_eid[c2], ei3 = csr_eid[c3];
        int s0 = srcv[ei0], s1 = srcv[ei1], s2 = srcv[ei2], s3 = srcv[ei3];

        const float4* p0 = (const float4*)(xl + (size_t)s0 * 128 + c);
        const float4* p1 = (const float4*)(xl + (size_t)s1 * 128 + c);
        const float4* p2 = (const float4*)(xl + (size_t)s2 * 128 + c);
        const float4* p3 = (const float4*)(xl + (size_t)s3 * 128 + c);
        float4 x0A = p0[0], x0B = p0[1];
        float4 x1A = p1[0], x1B = p1[1];
        float4 x2A = p2[0], x2B = p2[1];
        float4 x3A = p3[0], x3B = p3[1];
        const float4* q0 = (const float4*)(eattr + (size_t)ei0 * 8);
        const float4* q1 = (const float4*)(eattr + (size_t)ei1 * 8);
        const float4* q2 = (const float4*)(eattr + (size_t)ei2 * 8);
        const float4* q3 = (const float4*)(eattr + (size_t)ei3 * 8);
        float4 e0a = q0[0], e0b = q0[1];
        float4 e1a = q1[0], e1b = q1[1];
        float4 e2a = q2[0], e2b = q2[1];
        float4 e3a = q3[0], e3b = q3[1];

        auto logit = [&](float4 xA, float4 xB, float4 ea, float4 eb) -> float {
            float4 mA = f4add(xA, xrA), mB = f4add(xB, xrB);
            mA = f4fma(ea.x, WeA[0], mA); mB = f4fma(ea.x, WeB[0], mB);
            mA = f4fma(ea.y, WeA[1], mA); mB = f4fma(ea.y, WeB[1], mB);
            mA = f4fma(ea.z, WeA[2], mA); mB = f4fma(ea.z, WeB[2], mB);
            mA = f4fma(ea.w, WeA[3], mA); mB = f4fma(ea.w, WeB[3], mB);
            mA = f4fma(eb.x, WeA[4], mA); mB = f4fma(eb.x, WeB[4], mB);
            mA = f4fma(eb.y, WeA[5], mA); mB = f4fma(eb.y, WeB[5], mB);
            mA = f4fma(eb.z, WeA[6], mA); mB = f4fma(eb.z, WeB[6], mB);
            mA = f4fma(eb.w, WeA[7], mA); mB = f4fma(eb.w, WeB[7], mB);
            return f4dot(f4leaky(mA), attA) + f4dot(f4leaky(mB), attB);
        };

        float t0 = logit(x0A, x0B, e0a, e0b);
        float t1 = logit(x1A, x1B, e1a, e1b);
        float t2 = logit(x2A, x2B, e2a, e2b);
        float t3 = logit(x3A, x3B, e3a, e3b);
        #pragma unroll
        for (int off = 8; off; off >>= 1) {
            t0 += __shfl_xor(t0, off, 64);
            t1 += __shfl_xor(t1, off, 64);
            t2 += __shfl_xor(t2, off, 64);
            t3 += __shfl_xor(t3, off, 64);
        }

        if (i + 0 < cnt) {
            float nm = fmaxf(mrun, t0); float sc = __expf(mrun - nm); float p = __expf(t0 - nm);
            den = den * sc + p; accA = f4mix(sc, accA, p, x0A); accB = f4mix(sc, accB, p, x0B); mrun = nm;
        }
        if (i + 1 < cnt) {
            float nm = fmaxf(mrun, t1); float sc = __expf(mrun - nm); float p = __expf(t1 - nm);
            den = den * sc + p; accA = f4mix(sc, accA, p, x1A); accB = f4mix(sc, accB, p, x1B); mrun = nm;
        }
        if (i + 2 < cnt) {
            float nm = fmaxf(mrun, t2); float sc = __expf(mrun - nm); float p = __expf(t2 - nm);
            den = den * sc + p; accA = f4mix(sc, accA, p, x2A); accB = f4mix(sc, accB, p, x2B); mrun = nm;
        }
        if (i + 3 < cnt) {
            float nm = fmaxf(mrun, t3); float sc = __expf(mrun - nm); float p = __expf(t3 - nm);
            den = den * sc + p; accA = f4mix(sc, accA, p, x3A); accB = f4mix(sc, accB, p, x3B); mrun = nm;
        }
    }

    float inv = 1.f / fmaxf(den, 1e-16f);
    float4 oA = make_float4(accA.x * inv + bA.x, accA.y * inv + bA.y,
                            accA.z * inv + bA.z, accA.w * inv + bA.w);
    float4 oB = make_float4(accB.x * inv + bB.x, accB.y * inv + bB.y,
                            accB.z * inv + bB.z, accB.w * inv + bB.w);
    if (RELU) {
        oA = make_float4(fmaxf(oA.x,0.f), fmaxf(oA.y,0.f), fmaxf(oA.z,0.f), fmaxf(oA.w,0.f));
        oB = make_float4(fmaxf(oB.x,0.f), fmaxf(oB.y,0.f), fmaxf(oB.z,0.f), fmaxf(oB.w,0.f));
    }
    float ss = f4dot(oA, oA) + f4dot(oB, oB);
    #pragma unroll
    for (int off = 8; off; off >>= 1) ss += __shfl_xor(ss, off, 64);
    float innv = 1.f / fmaxf(sqrtf(ss), 1e-12f);
    oA = make_float4(oA.x * innv, oA.y * innv, oA.z * innv, oA.w * innv);
    oB = make_float4(oB.x * innv, oB.y * innv, oB.z * innv, oB.w * innv);
    if (has) {
        float4* op = (float4*)(out + (size_t)d * 128 + c);
        op[0] = oA;
        op[1] = oB;
        if (outb) {
            bf16x8 pk;
            pk[0] = f2bf(oA.x); pk[1] = f2bf(oA.y); pk[2] = f2bf(oA.z); pk[3] = f2bf(oA.w);
            pk[4] = f2bf(oB.x); pk[5] = f2bf(oB.y); pk[6] = f2bf(oB.z); pk[7] = f2bf(oB.w);
            *(bf16x8*)(outb + (size_t)d * 128 + c) = pk;
        }
    }
}

// ---------------- launch ----------------

extern "C" void kernel_launch(void* const* d_in, const int* in_sizes, int n_in,
                              void* d_out, int out_size, void* d_ws, size_t ws_size,
                              hipStream_t stream) {
    const float* x_artist = (const float*)d_in[0];
    const float* x_style  = (const float*)d_in[1];
    const int*   src_aa   = (const int*)d_in[2];
    const int*   dst_aa   = (const int*)d_in[3];
    const float* eattr_aa = (const float*)d_in[4];
    const int*   src_as   = (const int*)d_in[5];
    const int*   dst_as   = (const int*)d_in[6];
    const float* eattr_as = (const float*)d_in[7];
    const float* Wl0_aa = (const float*)d_in[8];
    const float* Wr0_aa = (const float*)d_in[9];
    const float* att0_aa = (const float*)d_in[10];
    const float* We0_aa = (const float*)d_in[11];
    const float* b0_aa = (const float*)d_in[12];
    const float* Wl0_as = (const float*)d_in[13];
    const float* Wr0_as = (const float*)d_in[14];
    const float* att0_as = (const float*)d_in[15];
    const float* We0_as = (const float*)d_in[16];
    const float* b0_as = (const float*)d_in[17];
    const float* Wl_aa = (const float*)d_in[18];
    const float* Wr_aa = (const float*)d_in[19];
    const float* att_aa = (const float*)d_in[20];
    const float* We_aa = (const float*)d_in[21];
    const float* b_aa = (const float*)d_in[22];
    const float* Wl_as = (const float*)d_in[23];
    const float* Wr_as = (const float*)d_in[24];
    const float* att_as = (const float*)d_in[25];
    const float* We_as = (const float*)d_in[26];
    const float* b_as = (const float*)d_in[27];

    float* out = (float*)d_out;

    // ws layout: bf16 buffers first (16B aligned), then floats, then ints
    short* Xb = (short*)d_ws;                     // [NAPAD][128] bf16
    short* Wt = Xb + (size_t)NAPAD * 128;         // [3][128][128] bf16 transposed
    float* fbase = (float*)(Wt + 3 * 16384);
    size_t off = 0;
    auto allocf = [&](size_t n) { float* r = fbase + off; off += n; return r; };
    float* hA0 = allocf((size_t)NA * CDIM);
    float* hA1 = allocf((size_t)NA * CDIM);
    float* hS0 = allocf((size_t)NS * CDIM);
    float* hS1 = allocf((size_t)NS * CDIM);
    float* bufA = allocf((size_t)NA * CDIM);   // xl_aa
    float* bufB = allocf((size_t)NA * CDIM);   // xr_aa
    float* bufD = allocf((size_t)NA * CDIM);   // xl_as
    float* bufC = allocf((size_t)NS * CDIM);   // xr_as
    int* ip = (int*)(fbase + off);
    int* rs_aa  = ip;            ip += NA + 1;
    int* cur_aa = ip;            ip += NA;
    int* csr_aa = ip;            ip += E_AA;
    int* rs_as  = ip;            ip += NS + 1;
    int* cur_as = ip;            ip += NS;
    int* csr_as = ip;            ip += E_AS;
    int* perm_aa = ip;           ip += NA;
    int* perm_as = ip;           ip += NS;
    int* dh   = ip;              ip += 256;
    int* dbo  = ip;              ip += 257;
    int* dcur = ip;              ip += 256;

    // ---- CSR + degree-sorted perm, AA ----
    hipMemsetAsync(cur_aa, 0, NA * sizeof(int), stream);
    count_k<<<(E_AA + 255) / 256, 256, 0, stream>>>(dst_aa, E_AA, cur_aa);
    scan_k<<<1, 1024, 0, stream>>>(cur_aa, rs_aa, NA);
    hipMemsetAsync(cur_aa, 0, NA * sizeof(int), stream);
    scatter_k<<<(E_AA + 255) / 256, 256, 0, stream>>>(dst_aa, E_AA, rs_aa, cur_aa, csr_aa);
    hipMemsetAsync(dh, 0, 256 * sizeof(int), stream);
    hipMemsetAsync(dcur, 0, 256 * sizeof(int), stream);
    deghist_k<<<(NA + 255) / 256, 256, 0, stream>>>(rs_aa, NA, dh);
    scan_k<<<1, 1024, 0, stream>>>(dh, dbo, 256);
    degscatter_k<<<(NA + 255) / 256, 256, 0, stream>>>(rs_aa, NA, dbo, dcur, perm_aa);

    // ---- CSR + degree-sorted perm, AS ----
    hipMemsetAsync(cur_as, 0, NS * sizeof(int), stream);
    count_k<<<(E_AS + 255) / 256, 256, 0, stream>>>(dst_as, E_AS, cur_as);
    scan_k<<<1, 1024, 0, stream>>>(cur_as, rs_as, NS);
    hipMemsetAsync(cur_as, 0, NS * sizeof(int), stream);
    scatter_k<<<(E_AS + 255) / 256, 256, 0, stream>>>(dst_as, E_AS, rs_as, cur_as, csr_as);
    hipMemsetAsync(dh, 0, 256 * sizeof(int), stream);
    hipMemsetAsync(dcur, 0, 256 * sizeof(int), stream);
    deghist_k<<<(NS + 255) / 256, 256, 0, stream>>>(rs_as, NS, dh);
    scan_k<<<1, 1024, 0, stream>>>(dh, dbo, 256);
    degscatter_k<<<(NS + 255) / 256, 256, 0, stream>>>(rs_as, NS, dbo, dcur, perm_as);

    // layer-0 X -> bf16
    cvt_k<<<(NA * CDIM / 4 + 255) / 256, 256, 0, stream>>>(x_artist, Xb, NA * CDIM / 4);

    const int gM = NAPAD / 64;              // 782 blocks for MFMA gemm
    const int gS = (NS + 31) / 32;
    const int aggA = (NA + 15) / 16;
    const int aggS = (NS + 15) / 16;

    const float* hS_in = x_style;

    for (int layer = 0; layer < 3; ++layer) {
        int j = layer - 1;
        const float *pWl_aa, *pWr_aa, *patt_aa, *pWe_aa, *pb_aa;
        const float *pWl_as, *pWr_as, *patt_as, *pWe_as, *pb_as;
        if (layer == 0) {
            pWl_aa = Wl0_aa; pWr_aa = Wr0_aa; patt_aa = att0_aa; pWe_aa = We0_aa; pb_aa = b0_aa;
            pWl_as = Wl0_as; pWr_as = Wr0_as; patt_as = att0_as; pWe_as = We0_as; pb_as = b0_as;
        } else {
            pWl_aa = Wl_aa + (size_t)j * CDIM * CDIM;
            pWr_aa = Wr_aa + (size_t)j * CDIM * CDIM;
            patt_aa = att_aa + (size_t)j * CDIM;
            pWe_aa = We_aa + (size_t)j * ED * CDIM;
            pb_aa = b_aa + (size_t)j * CDIM;
            pWl_as = Wl_as + (size_t)j * CDIM * CDIM;
            pWr_as = Wr_as + (size_t)j * CDIM * CDIM;
            patt_as = att_as + (size_t)j * CDIM;
            pWe_as = We_as + (size_t)j * ED * CDIM;
            pb_as = b_as + (size_t)j * CDIM;
        }
        float* hA_out = (layer == 2) ? out : (layer == 0 ? hA0 : hA1);
        float* hS_out = (layer == 2) ? out + (size_t)NA * CDIM : (layer == 0 ? hS0 : hS1);
        short* hA_outb = (layer == 2) ? nullptr : Xb;   // next layer's MFMA operand

        // transpose+convert this layer's three hA-side weights
        wtr_k<<<3 * 64, 256, 0, stream>>>(pWl_aa, pWr_aa, pWl_as, Wt);

        gemm3_mfma_k<<<gM, 256, 0, stream>>>(Xb, Wt, bufA, bufB, bufD, NA);
        if (layer == 0)
            gemm_k<64><<<gS, 256, 0, stream>>>(hS_in, pWr_as, bufC, NS);
        else
            gemm_k<128><<<gS, 256, 0, stream>>>(hS_in, pWr_as, bufC, NS);

        if (layer < 2) {
            agg_k<true><<<aggA, 256, 0, stream>>>(bufA, bufB, eattr_aa, src_aa, pWe_aa,
                                                  patt_aa, pb_aa, rs_aa, csr_aa, perm_aa,
                                                  hA_out, hA_outb, NA, E_AA);
            agg_k<true><<<aggS, 256, 0, stream>>>(bufD, bufC, eattr_as, src_as, pWe_as,
                                                  patt_as, pb_as, rs_as, csr_as, perm_as,
                                                  hS_out, nullptr, NS, E_AS);
        } else {
            agg_k<false><<<aggA, 256, 0, stream>>>(bufA, bufB, eattr_aa, src_aa, pWe_aa,
                                                   patt_aa, pb_aa, rs_aa, csr_aa, perm_aa,
                                                   hA_out, nullptr, NA, E_AA);
            agg_k<false><<<aggS, 256, 0, stream>>>(bufD, bufC, eattr_as, src_as, pWe_as,
                                                   patt_as, pb_as, rs_as, csr_as, perm_as,
                                                   hS_out, nullptr, NS, E_AS);
        }

        hS_in = hS_out;
    }
}